// Round 21
// baseline (960.731 us; speedup 1.0000x reference)
//
#include <hip/hip_runtime.h>
#include <hip/hip_fp16.h>

#define HIDDEN 256

using hfrag = __attribute__((ext_vector_type(8))) _Float16;  // 8 fp16
using facc16 = __attribute__((ext_vector_type(16))) float;   // 32x32 accum

// lgkm-only barrier: ds ops flushed, global loads STAY IN FLIGHT
#define BARRIER_LGKM()                                   \
  do {                                                   \
    asm volatile("s_waitcnt lgkmcnt(0)" ::: "memory");   \
    __builtin_amdgcn_s_barrier();                        \
  } while (0)

__device__ inline float h2f(unsigned short h) {
  return __half2float(__builtin_bit_cast(__half, h));
}
__device__ inline unsigned short f2h_bits(float v) {
  return __builtin_bit_cast(unsigned short, __float2half(v));
}
// 8 fp32 -> 8 fp16
__device__ inline hfrag f2h8(const float4& a, const float4& b) {
  hfrag h;
  h[0] = (_Float16)a.x; h[1] = (_Float16)a.y;
  h[2] = (_Float16)a.z; h[3] = (_Float16)a.w;
  h[4] = (_Float16)b.x; h[5] = (_Float16)b.y;
  h[6] = (_Float16)b.z; h[7] = (_Float16)b.w;
  return h;
}

// ---------------------------------------------------------------------------
// Parallel scan for CSR row_ptr (+fused dinv)
// ---------------------------------------------------------------------------
__global__ __launch_bounds__(256) void k_scan_a(const int* __restrict__ deg,
                                                int* __restrict__ bsum, int N) {
  const int t = threadIdx.x, lane = t & 63, w = t >> 6;
  const int idx = blockIdx.x * 256 + t;
  int x = (idx < N) ? deg[idx] : 0;
#pragma unroll
  for (int off = 32; off >= 1; off >>= 1) x += __shfl_xor(x, off);
  __shared__ int ws[4];
  if (lane == 0) ws[w] = x;
  __syncthreads();
  if (t == 0) bsum[blockIdx.x] = ws[0] + ws[1] + ws[2] + ws[3];
}

__global__ __launch_bounds__(512) void k_scan_b(const int* __restrict__ bsum,
                                                int* __restrict__ boff, int nb) {
  const int t = threadIdx.x, lane = t & 63, w = t >> 6;
  int orig = (t < nb) ? bsum[t] : 0;
  int x = orig;
#pragma unroll
  for (int off = 1; off < 64; off <<= 1) {
    int y = __shfl_up(x, off);
    if (lane >= off) x += y;
  }
  __shared__ int wsum[8];
  if (lane == 63) wsum[w] = x;
  __syncthreads();
  if (w == 0 && lane < 8) {
    int s = wsum[lane];
#pragma unroll
    for (int off = 1; off < 8; off <<= 1) {
      int y = __shfl_up(s, off);
      if (lane >= off) s += y;
    }
    wsum[lane] = s;
  }
  __syncthreads();
  int inc = x + (w > 0 ? wsum[w - 1] : 0);
  if (t < nb) boff[t] = inc - orig;
}

__global__ __launch_bounds__(256) void k_scan_c(const int* __restrict__ deg,
                                                const int* __restrict__ boff,
                                                int* __restrict__ row_ptr,
                                                float* __restrict__ dinv, int N) {
  const int t = threadIdx.x, lane = t & 63, w = t >> 6;
  const int idx = blockIdx.x * 256 + t;
  int d = (idx < N) ? deg[idx] : 0;
  int x = d;
#pragma unroll
  for (int off = 1; off < 64; off <<= 1) {
    int y = __shfl_up(x, off);
    if (lane >= off) x += y;
  }
  __shared__ int ws[4];
  if (lane == 63) ws[w] = x;
  __syncthreads();
  int add = boff[blockIdx.x];
#pragma unroll
  for (int j = 0; j < 4; ++j)
    if (j < w) add += ws[j];
  if (idx < N) {
    row_ptr[idx + 1] = x + add;
    dinv[idx] = 1.0f / sqrtf((float)d + 1.0f);  // +1 self loop
  }
  if (idx == 0) row_ptr[0] = 0;
}

// ---------------------------------------------------------------------------
// Weight prep: split-f16 planes in WAVE-COALESCED fragment order (+ fused
// zeroing of deg/fill: grid covers N). Per 32-k tile (16384 sh):
// [wave w (n>>6): 4096][frag nt*2+kh: 512, hi | +2048 lo][lane: 8][j].
// Offsets (shorts): W_in at 0 (24 tiles), layer l at 393216 + l*131072.
// ---------------------------------------------------------------------------
__global__ __launch_bounds__(256) void k_prep_w(const float* __restrict__ W_in,
                                                const float* __restrict__ W_g,
                                                short* __restrict__ Wt,
                                                int* __restrict__ deg,
                                                int* __restrict__ fill, int N) {
  const int e = blockIdx.x * blockDim.x + threadIdx.x;
  if (e < N) {
    deg[e] = 0;
    fill[e] = 0;
  }
  if (e >= 196608 + 3 * 65536) return;
  float v;
  int k, n;
  size_t base;
  if (e < 196608) {           // W_in [768][256]
    k = e >> 8;
    n = e & 255;
    v = W_in[e];
    base = 0;
  } else {                    // W_g [3][256][256]
    int r = e - 196608;
    int lyr = r >> 16;
    k = (r >> 8) & 255;
    n = r & 255;
    v = W_g[r];
    base = 393216 + (size_t)lyr * 131072;
  }
  const int s = k >> 5;
  const int w = n >> 6, nt = (n >> 5) & 1, l31 = n & 31;
  const int kh = (k >> 4) & 1, g2 = (k >> 3) & 1, j = k & 7;
  size_t pos = base + (size_t)s * 16384 + (size_t)w * 4096 +
               (size_t)(nt * 2 + kh) * 512 + (size_t)(g2 * 32 + l31) * 8 + j;
  __half hh = __float2half(v);
  float r2 = v - __half2float(hh);
  Wt[pos] = (short)__builtin_bit_cast(unsigned short, hh);
  Wt[pos + 2048] = (short)__builtin_bit_cast(unsigned short, __float2half(r2));
}

// ---------------------------------------------------------------------------
// Shared B-load + MFMA macros (32x32x16_f16, wave tile 64x64, 2x2 frags)
// wb = Wt + w*4096 + lane*8 ; each load = contiguous 1KB per wave.
// ---------------------------------------------------------------------------
#define B_LOAD(S, BH, BL)                                               \
  {                                                                     \
    const short* wp = wb + ((size_t)(S) << 14);                         \
    BH[0][0] = *(const hfrag*)(wp);                                     \
    BH[0][1] = *(const hfrag*)(wp + 512);                               \
    BH[1][0] = *(const hfrag*)(wp + 1024);                              \
    BH[1][1] = *(const hfrag*)(wp + 1536);                              \
    BL[0][0] = *(const hfrag*)(wp + 2048);                              \
    BL[0][1] = *(const hfrag*)(wp + 2048 + 512);                        \
    BL[1][0] = *(const hfrag*)(wp + 2048 + 1024);                       \
    BL[1][1] = *(const hfrag*)(wp + 2048 + 1536);                       \
  }

#define TILE_COMPUTE(AA, BH, BL)                                        \
  _Pragma("unroll") for (int kh = 0; kh < 2; ++kh) {                    \
    _Pragma("unroll") for (int mt = 0; mt < 2; ++mt)                    \
        _Pragma("unroll") for (int nt = 0; nt < 2; ++nt) acc[mt][nt] =  \
        __builtin_amdgcn_mfma_f32_32x32x16_f16(AA[mt][kh], BH[nt][kh],  \
                                               acc[mt][nt], 0, 0, 0);   \
    _Pragma("unroll") for (int mt = 0; mt < 2; ++mt)                    \
        _Pragma("unroll") for (int nt = 0; nt < 2; ++nt) acc[mt][nt] =  \
        __builtin_amdgcn_mfma_f32_32x32x16_f16(AA[mt][kh], BL[nt][kh],  \
                                               acc[mt][nt], 0, 0, 0);   \
  }

// ---------------------------------------------------------------------------
// Proj GEMM body (R18 structure -- best measured): A = fp16(x) single,
// B = split-f16 2-pass single-buffered, 32x32x16_f16, LDS A-dbuf [2][64][34],
// lgkm barriers, A reg-prefetch. Out: fp16 h0 = relu(x@W_in + b_in).
// ---------------------------------------------------------------------------
__device__ __forceinline__ void proj_body(int bx, const float* __restrict__ A,
                                          const short* __restrict__ Wt,
                                          const float* __restrict__ bias,
                                          unsigned short* __restrict__ Ch,
                                          int M, int K) {
  __shared__ short As[2][64][34];  // fp16 A tile: 32 data + 2 pad
  const int t = threadIdx.x;
  const int w = t >> 6, l = t & 63;
  const int g2 = l >> 5, l31 = l & 31;
  const int row0 = bx * 64;
  const int colbase = w * 64;
  const int arow = t >> 2, ak = (t & 3) << 3;

  facc16 acc[2][2];
#pragma unroll
  for (int i = 0; i < 2; ++i)
#pragma unroll
    for (int j = 0; j < 2; ++j) acc[i][j] = (facc16)(0.0f);

  const int nsteps = K >> 5;
  const int ga = row0 + arow;
  const bool aval = ga < M;
  const float* aptr = A + (size_t)ga * K + ak;
  const short* wb = Wt + (size_t)w * 4096 + (size_t)l * 8;

  float4 f0 = make_float4(0.f, 0.f, 0.f, 0.f), f1 = f0;
  if (aval) {
    f0 = *(const float4*)aptr;
    f1 = *(const float4*)(aptr + 4);
  }
  *(hfrag*)&As[0][arow][ak] = f2h8(f0, f1);
  if (nsteps > 1 && aval) {
    f0 = *(const float4*)(aptr + 32);
    f1 = *(const float4*)(aptr + 36);
  }

  int cur = 0;
  for (int s = 0; s < nsteps; ++s) {
    BARRIER_LGKM();
    hfrag bh[2][2], bl[2][2];
    B_LOAD(s, bh, bl);
    // compute: per khalf, 2 A ds_reads + 8 MFMAs (2 passes)
#pragma unroll
    for (int kh = 0; kh < 2; ++kh) {
      hfrag ah[2];
#pragma unroll
      for (int mt = 0; mt < 2; ++mt)
        ah[mt] = *(const hfrag*)&As[cur][mt * 32 + l31][kh * 16 + g2 * 8];
#pragma unroll
      for (int mt = 0; mt < 2; ++mt)
#pragma unroll
        for (int nt = 0; nt < 2; ++nt)
          acc[mt][nt] = __builtin_amdgcn_mfma_f32_32x32x16_f16(
              ah[mt], bh[nt][kh], acc[mt][nt], 0, 0, 0);
#pragma unroll
      for (int mt = 0; mt < 2; ++mt)
#pragma unroll
        for (int nt = 0; nt < 2; ++nt)
          acc[mt][nt] = __builtin_amdgcn_mfma_f32_32x32x16_f16(
              ah[mt], bl[nt][kh], acc[mt][nt], 0, 0, 0);
    }
    // stage next tile; prefetch one further
    if (s + 1 < nsteps) {
      *(hfrag*)&As[cur ^ 1][arow][ak] = f2h8(f0, f1);
      if (s + 2 < nsteps && aval) {
        const float* ap = aptr + (size_t)(s + 2) * 32;
        f0 = *(const float4*)(ap + 0);
        f1 = *(const float4*)(ap + 4);
      }
    }
    cur ^= 1;
  }
  // epilogue: C/D col=lane&31, row=(reg&3)+8*(reg>>2)+4*g2; fp16 out
#pragma unroll
  for (int nt = 0; nt < 2; ++nt) {
    const int col = colbase + nt * 32 + l31;
    const float b = bias[col];
#pragma unroll
    for (int mt = 0; mt < 2; ++mt)
#pragma unroll
      for (int r = 0; r < 16; ++r) {
        int row = row0 + mt * 32 + (r & 3) + 8 * (r >> 2) + 4 * g2;
        if (row < M)
          Ch[(size_t)row * HIDDEN + col] = f2h_bits(fmaxf(acc[mt][nt][r] + b, 0.f));
      }
  }
}

// ---------------------------------------------------------------------------
// Layer GEMM body: A = fp16 h global, B = split-f16 planes (coalesced),
// 2 passes, register dbuf one K-step ahead. Out: fp16 m' = dinv[row]*(A@B).
// ---------------------------------------------------------------------------
#define LG_LOAD(S, AA, BH, BL)                                          \
  {                                                                     \
    AA[0][0] = *(const hfrag*)(ap0 + (S) * 32);                         \
    AA[0][1] = *(const hfrag*)(ap0 + (S) * 32 + 16);                    \
    AA[1][0] = *(const hfrag*)(ap1 + (S) * 32);                         \
    AA[1][1] = *(const hfrag*)(ap1 + (S) * 32 + 16);                    \
    B_LOAD(S, BH, BL);                                                  \
  }

__device__ __forceinline__ void layer_gemm_body(
    int bx, const unsigned short* __restrict__ A, const short* __restrict__ Wt,
    const float* __restrict__ dinv, unsigned short* __restrict__ Cm, int M) {
  const int t = threadIdx.x;
  const int w = t >> 6, l = t & 63;
  const int g2 = l >> 5, l31 = l & 31;
  const int row0 = bx * 64;
  const int colbase = w * 64;

  facc16 acc[2][2];
#pragma unroll
  for (int i = 0; i < 2; ++i)
#pragma unroll
    for (int j = 0; j < 2; ++j) acc[i][j] = (facc16)(0.0f);

  int r0 = row0 + l31, r1 = row0 + 32 + l31;
  if (r0 >= M) r0 = M - 1;
  if (r1 >= M) r1 = M - 1;
  const unsigned short* ap0 = A + (size_t)r0 * HIDDEN + g2 * 8;
  const unsigned short* ap1 = A + (size_t)r1 * HIDDEN + g2 * 8;
  const short* wb = Wt + (size_t)w * 4096 + (size_t)l * 8;

  hfrag aA[2][2], bhA[2][2], blA[2][2];
  hfrag aB[2][2], bhB[2][2], blB[2][2];

  LG_LOAD(0, aA, bhA, blA);
#pragma unroll
  for (int s = 0; s < 8; s += 2) {
    if (s + 1 < 8) LG_LOAD(s + 1, aB, bhB, blB);
    TILE_COMPUTE(aA, bhA, blA);
    if (s + 2 < 8) LG_LOAD(s + 2, aA, bhA, blA);
    TILE_COMPUTE(aB, bhB, blB);
  }
#pragma unroll
  for (int mt = 0; mt < 2; ++mt)
#pragma unroll
    for (int r = 0; r < 16; ++r) {
      int row = row0 + mt * 32 + (r & 3) + 8 * (r >> 2) + 4 * g2;
      if (row >= M) continue;
      const float sc = dinv[row];
#pragma unroll
      for (int nt = 0; nt < 2; ++nt)
        Cm[(size_t)row * HIDDEN + colbase + nt * 32 + l31] =
            f2h_bits(acc[mt][nt][r] * sc);
    }
}

// ---------------------------------------------------------------------------
// MEGA1: proj GEMM (blocks [0,ngemm)) || dst-degree histogram (rest)
// ---------------------------------------------------------------------------
__global__ __launch_bounds__(256, 4) void k_mega1(
    const float* __restrict__ x, const short* __restrict__ Wt,
    const float* __restrict__ b_in, unsigned short* __restrict__ h0, int M,
    int K, const int* __restrict__ dst, int* __restrict__ deg, int E,
    int ngemm, int nhist) {
  if ((int)blockIdx.x < ngemm) {
    proj_body(blockIdx.x, x, Wt, b_in, h0, M, K);
  } else {
    const int b = blockIdx.x - ngemm;
    for (int e = b * 256 + threadIdx.x; e < E; e += nhist * 256)
      atomicAdd(&deg[dst[e]], 1);
  }
}

// ---------------------------------------------------------------------------
// MEGA2: layer-0 GEMM (blocks [0,ngemm)) || CSR fill (rest)
// ---------------------------------------------------------------------------
__global__ __launch_bounds__(256, 2) void k_mega2(
    const unsigned short* __restrict__ h0, const short* __restrict__ WtL,
    const float* __restrict__ dinv, unsigned short* __restrict__ h1, int M,
    const int* __restrict__ src, const int* __restrict__ dst,
    const int* __restrict__ row_ptr, int* __restrict__ fill,
    int* __restrict__ csr, int E, int ngemm, int nfill) {
  if ((int)blockIdx.x < ngemm) {
    layer_gemm_body(blockIdx.x, h0, WtL, dinv, h1, M);
  } else {
    const int b = blockIdx.x - ngemm;
    for (int e = b * 256 + threadIdx.x; e < E; e += nfill * 256) {
      int d = dst[e];
      int pos = atomicAdd(&fill[d], 1);
      csr[row_ptr[d] + pos] = src[e];
    }
  }
}

__global__ __launch_bounds__(256, 2) void k_gemm_layer(
    const unsigned short* __restrict__ h, const short* __restrict__ WtL,
    const float* __restrict__ dinv, unsigned short* __restrict__ m, int M) {
  layer_gemm_body(blockIdx.x, h, WtL, dinv, m, M);
}

// ---------------------------------------------------------------------------
// Gather aggregation + bias + BN + ReLU over fp16 m'; fp16 h out.
// TWO nodes per wave: half-wave (32 lanes) covers one 512B row; lane owns
// 8 channels (uint4 = 16B). 8-row unroll.
// ---------------------------------------------------------------------------
__device__ inline void addrow8(float* acc, const uint4& r) {
  const unsigned short* p = (const unsigned short*)&r;
#pragma unroll
  for (int j = 0; j < 8; ++j) acc[j] += h2f(p[j]);
}

__global__ __launch_bounds__(256) void k_aggregate(
    const unsigned short* __restrict__ mp, const int* __restrict__ row_ptr,
    const int* __restrict__ csr, const float* __restrict__ dinv,
    const float* __restrict__ bg, const float* __restrict__ gamma,
    const float* __restrict__ beta, const float* __restrict__ mean,
    const float* __restrict__ var, unsigned short* __restrict__ hout, int N) {
  const int wave = threadIdx.x >> 6, l = threadIdx.x & 63;
  const int half = l >> 5, l31 = l & 31;
  const int v = blockIdx.x * 8 + wave * 2 + half;
  if (v >= N) return;
  const int co = l31 << 3;  // 8 channels per lane
  float acc[8];
  {
    uint4 rs = *(const uint4*)(mp + (size_t)v * HIDDEN + co);  // self loop
    const unsigned short* p = (const unsigned short*)&rs;
#pragma unroll
    for (int j = 0; j < 8; ++j) acc[j] = h2f(p[j]);
  }
  const int s = row_ptr[v], e = row_ptr[v + 1];
  int i = s;
  for (; i + 8 <= e; i += 8) {
    uint4 r[8];
#pragma unroll
    for (int j = 0; j < 8; ++j)
      r[j] = *(const uint4*)(mp + (size_t)csr[i + j] * HIDDEN + co);
#pragma unroll
    for (int j = 0; j < 8; ++j) addrow8(acc, r[j]);
  }
  for (; i < e; ++i) {
    uint4 r0 = *(const uint4*)(mp + (size_t)csr[i] * HIDDEN + co);
    addrow8(acc, r0);
  }
  const float dv = dinv[v];
  float4 g4a = *(const float4*)&gamma[co], g4b = *(const float4*)&gamma[co + 4];
  float4 vr4a = *(const float4*)&var[co], vr4b = *(const float4*)&var[co + 4];
  float4 bg4a = *(const float4*)&bg[co], bg4b = *(const float4*)&bg[co + 4];
  float4 mn4a = *(const float4*)&mean[co], mn4b = *(const float4*)&mean[co + 4];
  float4 be4a = *(const float4*)&beta[co], be4b = *(const float4*)&beta[co + 4];
  float sc[8] = {g4a.x / sqrtf(vr4a.x + 1e-5f), g4a.y / sqrtf(vr4a.y + 1e-5f),
                 g4a.z / sqrtf(vr4a.z + 1e-5f), g4a.w / sqrtf(vr4a.w + 1e-5f),
                 g4b.x / sqrtf(vr4b.x + 1e-5f), g4b.y / sqrtf(vr4b.y + 1e-5f),
                 g4b.z / sqrtf(vr4b.z + 1e-5f), g4b.w / sqrtf(vr4b.w + 1e-5f)};
  float ofs[8] = {bg4a.x - mn4a.x, bg4a.y - mn4a.y, bg4a.z - mn4a.z,
                  bg4a.w - mn4a.w, bg4b.x - mn4b.x, bg4b.y - mn4b.y,
                  bg4b.z - mn4b.z, bg4b.w - mn4b.w};
  float bt[8] = {be4a.x, be4a.y, be4a.z, be4a.w, be4b.x, be4b.y, be4b.z, be4b.w};
  unsigned short o[8];
#pragma unroll
  for (int j = 0; j < 8; ++j)
    o[j] = f2h_bits(fmaxf((acc[j] * dv + ofs[j]) * sc[j] + bt[j], 0.f));
  *(uint4*)&hout[(size_t)v * HIDDEN + co] = *(const uint4*)o;
}

// ---------------------------------------------------------------------------
// FUSED mean-pool + head MLP: one 256-thread block per graph. batch is
// sorted -> graph g owns contiguous rows [lo,hi) found by binary search.
// Phase 1: thread t sums channel t over the range (coalesced 512B/row).
// Phase 2: out = relu(g@W1+b1)@W2+b2 in-block.
// ---------------------------------------------------------------------------
__global__ __launch_bounds__(256) void k_poolhead(
    const unsigned short* __restrict__ h, const int* __restrict__ batch, int N,
    const float* __restrict__ W1, const float* __restrict__ b1,
    const float* __restrict__ W2, const float* __restrict__ b2,
    float* __restrict__ out) {
  __shared__ float gr[256];
  __shared__ float t1[128];
  __shared__ int range[2];
  const int b = blockIdx.x, t = threadIdx.x;
  if (t < 2) {
    const int target = b + t;  // t=0: first idx of b; t=1: first idx of b+1
    int lo = 0, hi = N;
    while (lo < hi) {
      int mid = (lo + hi) >> 1;
      if (batch[mid] < target) lo = mid + 1; else hi = mid;
    }
    range[t] = lo;
  }
  __syncthreads();
  const int lo = range[0], hi = range[1];
  float acc = 0.f;
  int n = lo;
  for (; n + 4 <= hi; n += 4) {
    unsigned short a0 = h[(size_t)(n + 0) * HIDDEN + t];
    unsigned short a1 = h[(size_t)(n + 1) * HIDDEN + t];
    unsigned short a2 = h[(size_t)(n + 2) * HIDDEN + t];
    unsigned short a3 = h[(size_t)(n + 3) * HIDDEN + t];
    acc += h2f(a0) + h2f(a1) + h2f(a2) + h2f(a3);
  }
  for (; n < hi; ++n) acc += h2f(h[(size_t)n * HIDDEN + t]);
  const float inv = 1.0f / fmaxf((float)(hi - lo), 1.0f);
  gr[t] = acc * inv;
  __syncthreads();
  if (t < 128) {
    float a = b1[t];
    for (int k = 0; k < 256; ++k) a += gr[k] * W1[k * 128 + t];
    t1[t] = fmaxf(a, 0.f);
  }
  __syncthreads();
  if (t < 128) {
    float o = b2[t];
    for (int k = 0; k < 128; ++k) o += t1[k] * W2[k * 128 + t];
    out[b * 128 + t] = o;
  }
}

// ---------------------------------------------------------------------------
extern "C" void kernel_launch(void* const* d_in, const int* in_sizes, int n_in,
                              void* d_out, int out_size, void* d_ws,
                              size_t ws_size, hipStream_t stream) {
  (void)n_in;
  (void)ws_size;
  const float* x = (const float*)d_in[0];
  const int* ei = (const int*)d_in[1];
  const int* batch = (const int*)d_in[2];
  const float* W_in = (const float*)d_in[3];
  const float* b_in = (const float*)d_in[4];
  const float* W_g = (const float*)d_in[5];
  const float* b_g = (const float*)d_in[6];
  const float* bn_gamma = (const float*)d_in[7];
  const float* bn_beta = (const float*)d_in[8];
  const float* bn_mean = (const float*)d_in[9];
  const float* bn_var = (const float*)d_in[10];
  const float* W1 = (const float*)d_in[11];
  const float* b1 = (const float*)d_in[12];
  const float* W2 = (const float*)d_in[13];
  const float* b2 = (const float*)d_in[14];

  const int KIN = 768;
  const int N = in_sizes[0] / KIN;   // 100000
  const int E = in_sizes[1] / 2;     // 1600000
  const int G = out_size / 128;      // 64

  const int* src = ei;
  const int* dst = ei + E;

  char* ws = (char*)d_ws;
  size_t off = 0;
  auto take = [&](size_t bytes) -> void* {
    void* p = ws + off;
    off += (bytes + 255) & ~(size_t)255;
    return p;
  };
  unsigned short* h0 = (unsigned short*)take((size_t)N * HIDDEN * 2);  // fp16 h
  unsigned short* h1 = (unsigned short*)take((size_t)N * HIDDEN * 2);  // fp16 m'
  float* dinv = (float*)take((size_t)N * 4);
  int* deg = (int*)take((size_t)N * 4);
  int* fill = (int*)take((size_t)N * 4);
  int* row_ptr = (int*)take((size_t)(N + 1) * 4);
  int* csr = (int*)take((size_t)E * 4);
  short* Wt = (short*)take((size_t)(393216 + 3 * 131072) * 2);
  const int nb = (N + 255) / 256;
  int* bsum = (int*)take((size_t)nb * 4);
  int* boff = (int*)take((size_t)nb * 4);

  const int gx = (N + 63) / 64;
  const int NH = 256;  // hist blocks in mega1
  const int NF = 256;  // fill blocks in mega2

  // prep (also zeroes deg/fill; its grid covers N)
  k_prep_w<<<(196608 + 3 * 65536 + 255) / 256, 256, 0, stream>>>(
      W_in, W_g, Wt, deg, fill, N);
  // proj GEMM || hist
  k_mega1<<<gx + NH, 256, 0, stream>>>(x, Wt, b_in, h0, N, KIN, dst, deg, E,
                                       gx, NH);
  k_scan_a<<<nb, 256, 0, stream>>>(deg, bsum, N);
  k_scan_b<<<1, 512, 0, stream>>>(bsum, boff, nb);
  k_scan_c<<<nb, 256, 0, stream>>>(deg, boff, row_ptr, dinv, N);
  // layer-0 GEMM || fill   (h0 -> h1 = m')
  k_mega2<<<gx + NF, 256, 0, stream>>>(h0, Wt + 393216, dinv, h1, N, src, dst,
                                       row_ptr, fill, csr, E, gx, NF);
  k_aggregate<<<(N + 7) / 8, 256, 0, stream>>>(
      h1, row_ptr, csr, dinv, b_g, bn_gamma, bn_beta, bn_mean, bn_var, h0, N);
  for (int i = 1; i < 3; ++i) {
    k_gemm_layer<<<gx, 256, 0, stream>>>(h0, Wt + 393216 + (size_t)i * 131072,
                                         dinv, h1, N);
    k_aggregate<<<(N + 7) / 8, 256, 0, stream>>>(
        h1, row_ptr, csr, dinv, b_g + i * HIDDEN, bn_gamma + i * HIDDEN,
        bn_beta + i * HIDDEN, bn_mean + i * HIDDEN, bn_var + i * HIDDEN, h0, N);
  }
  k_poolhead<<<G, 256, 0, stream>>>(h0, batch, N, W1, b1, W2, b2,
                                    (float*)d_out);
}

// Round 22
// 934.276 us; speedup vs baseline: 1.0283x; 1.0283x over previous
//
#include <hip/hip_runtime.h>
#include <hip/hip_fp16.h>

#define HIDDEN 256

using hfrag = __attribute__((ext_vector_type(8))) _Float16;  // 8 fp16
using facc16 = __attribute__((ext_vector_type(16))) float;   // 32x32 accum

// lgkm-only barrier: ds ops flushed, global loads STAY IN FLIGHT
#define BARRIER_LGKM()                                   \
  do {                                                   \
    asm volatile("s_waitcnt lgkmcnt(0)" ::: "memory");   \
    __builtin_amdgcn_s_barrier();                        \
  } while (0)

__device__ inline float h2f(unsigned short h) {
  return __half2float(__builtin_bit_cast(__half, h));
}
__device__ inline unsigned short f2h_bits(float v) {
  return __builtin_bit_cast(unsigned short, __float2half(v));
}
// 8 fp32 -> 8 fp16
__device__ inline hfrag f2h8(const float4& a, const float4& b) {
  hfrag h;
  h[0] = (_Float16)a.x; h[1] = (_Float16)a.y;
  h[2] = (_Float16)a.z; h[3] = (_Float16)a.w;
  h[4] = (_Float16)b.x; h[5] = (_Float16)b.y;
  h[6] = (_Float16)b.z; h[7] = (_Float16)b.w;
  return h;
}

// ---------------------------------------------------------------------------
// Parallel scan for CSR row_ptr (+fused dinv)
// ---------------------------------------------------------------------------
__global__ __launch_bounds__(256) void k_scan_a(const int* __restrict__ deg,
                                                int* __restrict__ bsum, int N) {
  const int t = threadIdx.x, lane = t & 63, w = t >> 6;
  const int idx = blockIdx.x * 256 + t;
  int x = (idx < N) ? deg[idx] : 0;
#pragma unroll
  for (int off = 32; off >= 1; off >>= 1) x += __shfl_xor(x, off);
  __shared__ int ws[4];
  if (lane == 0) ws[w] = x;
  __syncthreads();
  if (t == 0) bsum[blockIdx.x] = ws[0] + ws[1] + ws[2] + ws[3];
}

__global__ __launch_bounds__(512) void k_scan_b(const int* __restrict__ bsum,
                                                int* __restrict__ boff, int nb) {
  const int t = threadIdx.x, lane = t & 63, w = t >> 6;
  int orig = (t < nb) ? bsum[t] : 0;
  int x = orig;
#pragma unroll
  for (int off = 1; off < 64; off <<= 1) {
    int y = __shfl_up(x, off);
    if (lane >= off) x += y;
  }
  __shared__ int wsum[8];
  if (lane == 63) wsum[w] = x;
  __syncthreads();
  if (w == 0 && lane < 8) {
    int s = wsum[lane];
#pragma unroll
    for (int off = 1; off < 8; off <<= 1) {
      int y = __shfl_up(s, off);
      if (lane >= off) s += y;
    }
    wsum[lane] = s;
  }
  __syncthreads();
  int inc = x + (w > 0 ? wsum[w - 1] : 0);
  if (t < nb) boff[t] = inc - orig;
}

__global__ __launch_bounds__(256) void k_scan_c(const int* __restrict__ deg,
                                                const int* __restrict__ boff,
                                                int* __restrict__ row_ptr,
                                                float* __restrict__ dinv, int N) {
  const int t = threadIdx.x, lane = t & 63, w = t >> 6;
  const int idx = blockIdx.x * 256 + t;
  int d = (idx < N) ? deg[idx] : 0;
  int x = d;
#pragma unroll
  for (int off = 1; off < 64; off <<= 1) {
    int y = __shfl_up(x, off);
    if (lane >= off) x += y;
  }
  __shared__ int ws[4];
  if (lane == 63) ws[w] = x;
  __syncthreads();
  int add = boff[blockIdx.x];
#pragma unroll
  for (int j = 0; j < 4; ++j)
    if (j < w) add += ws[j];
  if (idx < N) {
    row_ptr[idx + 1] = x + add;
    dinv[idx] = 1.0f / sqrtf((float)d + 1.0f);  // +1 self loop
  }
  if (idx == 0) row_ptr[0] = 0;
}

// ---------------------------------------------------------------------------
// Weight prep: split-f16 planes in WAVE-COALESCED fragment order (+ fused
// zeroing of deg/fill/sums). Per 32-k tile (16384 sh):
// [wave w (n>>6): 4096][frag nt*2+kh: 512, hi | +2048 lo][lane: 8][j].
// Offsets (shorts): W_in at 0 (24 tiles), layer l at 393216 + l*131072.
// ---------------------------------------------------------------------------
__global__ __launch_bounds__(256) void k_prep_w(const float* __restrict__ W_in,
                                                const float* __restrict__ W_g,
                                                short* __restrict__ Wt,
                                                int* __restrict__ deg,
                                                int* __restrict__ fill, int N,
                                                float* __restrict__ sums,
                                                int nsum) {
  const int e = blockIdx.x * blockDim.x + threadIdx.x;
  if (e < N) {
    deg[e] = 0;
    fill[e] = 0;
  }
  if (e < nsum) sums[e] = 0.f;
  if (e >= 196608 + 3 * 65536) return;
  float v;
  int k, n;
  size_t base;
  if (e < 196608) {           // W_in [768][256]
    k = e >> 8;
    n = e & 255;
    v = W_in[e];
    base = 0;
  } else {                    // W_g [3][256][256]
    int r = e - 196608;
    int lyr = r >> 16;
    k = (r >> 8) & 255;
    n = r & 255;
    v = W_g[r];
    base = 393216 + (size_t)lyr * 131072;
  }
  const int s = k >> 5;
  const int w = n >> 6, nt = (n >> 5) & 1, l31 = n & 31;
  const int kh = (k >> 4) & 1, g2 = (k >> 3) & 1, j = k & 7;
  size_t pos = base + (size_t)s * 16384 + (size_t)w * 4096 +
               (size_t)(nt * 2 + kh) * 512 + (size_t)(g2 * 32 + l31) * 8 + j;
  __half hh = __float2half(v);
  float r2 = v - __half2float(hh);
  Wt[pos] = (short)__builtin_bit_cast(unsigned short, hh);
  Wt[pos + 2048] = (short)__builtin_bit_cast(unsigned short, __float2half(r2));
}

// ---------------------------------------------------------------------------
// Shared B-load + MFMA macros (32x32x16_f16, wave tile 64x64, 2x2 frags)
// wb = Wt + w*4096 + lane*8 ; each load = contiguous 1KB per wave.
// ---------------------------------------------------------------------------
#define B_LOAD(S, BH, BL)                                               \
  {                                                                     \
    const short* wp = wb + ((size_t)(S) << 14);                         \
    BH[0][0] = *(const hfrag*)(wp);                                     \
    BH[0][1] = *(const hfrag*)(wp + 512);                               \
    BH[1][0] = *(const hfrag*)(wp + 1024);                              \
    BH[1][1] = *(const hfrag*)(wp + 1536);                              \
    BL[0][0] = *(const hfrag*)(wp + 2048);                              \
    BL[0][1] = *(const hfrag*)(wp + 2048 + 512);                        \
    BL[1][0] = *(const hfrag*)(wp + 2048 + 1024);                       \
    BL[1][1] = *(const hfrag*)(wp + 2048 + 1536);                       \
  }

#define TILE_COMPUTE(AA, BH, BL)                                        \
  _Pragma("unroll") for (int kh = 0; kh < 2; ++kh) {                    \
    _Pragma("unroll") for (int mt = 0; mt < 2; ++mt)                    \
        _Pragma("unroll") for (int nt = 0; nt < 2; ++nt) acc[mt][nt] =  \
        __builtin_amdgcn_mfma_f32_32x32x16_f16(AA[mt][kh], BH[nt][kh],  \
                                               acc[mt][nt], 0, 0, 0);   \
    _Pragma("unroll") for (int mt = 0; mt < 2; ++mt)                    \
        _Pragma("unroll") for (int nt = 0; nt < 2; ++nt) acc[mt][nt] =  \
        __builtin_amdgcn_mfma_f32_32x32x16_f16(AA[mt][kh], BL[nt][kh],  \
                                               acc[mt][nt], 0, 0, 0);   \
  }

// ---------------------------------------------------------------------------
// Proj GEMM body (R18 structure -- best measured): A = fp16(x) single,
// B = split-f16 2-pass single-buffered, 32x32x16_f16, LDS A-dbuf [2][64][34],
// lgkm barriers, A reg-prefetch. Out: fp16 h0 = relu(x@W_in + b_in).
// ---------------------------------------------------------------------------
__device__ __forceinline__ void proj_body(int bx, const float* __restrict__ A,
                                          const short* __restrict__ Wt,
                                          const float* __restrict__ bias,
                                          unsigned short* __restrict__ Ch,
                                          int M, int K) {
  __shared__ short As[2][64][34];  // fp16 A tile: 32 data + 2 pad
  const int t = threadIdx.x;
  const int w = t >> 6, l = t & 63;
  const int g2 = l >> 5, l31 = l & 31;
  const int row0 = bx * 64;
  const int colbase = w * 64;
  const int arow = t >> 2, ak = (t & 3) << 3;

  facc16 acc[2][2];
#pragma unroll
  for (int i = 0; i < 2; ++i)
#pragma unroll
    for (int j = 0; j < 2; ++j) acc[i][j] = (facc16)(0.0f);

  const int nsteps = K >> 5;
  const int ga = row0 + arow;
  const bool aval = ga < M;
  const float* aptr = A + (size_t)ga * K + ak;
  const short* wb = Wt + (size_t)w * 4096 + (size_t)l * 8;

  float4 f0 = make_float4(0.f, 0.f, 0.f, 0.f), f1 = f0;
  if (aval) {
    f0 = *(const float4*)aptr;
    f1 = *(const float4*)(aptr + 4);
  }
  *(hfrag*)&As[0][arow][ak] = f2h8(f0, f1);
  if (nsteps > 1 && aval) {
    f0 = *(const float4*)(aptr + 32);
    f1 = *(const float4*)(aptr + 36);
  }

  int cur = 0;
  for (int s = 0; s < nsteps; ++s) {
    BARRIER_LGKM();
    hfrag bh[2][2], bl[2][2];
    B_LOAD(s, bh, bl);
    // compute: per khalf, 2 A ds_reads + 8 MFMAs (2 passes)
#pragma unroll
    for (int kh = 0; kh < 2; ++kh) {
      hfrag ah[2];
#pragma unroll
      for (int mt = 0; mt < 2; ++mt)
        ah[mt] = *(const hfrag*)&As[cur][mt * 32 + l31][kh * 16 + g2 * 8];
#pragma unroll
      for (int mt = 0; mt < 2; ++mt)
#pragma unroll
        for (int nt = 0; nt < 2; ++nt)
          acc[mt][nt] = __builtin_amdgcn_mfma_f32_32x32x16_f16(
              ah[mt], bh[nt][kh], acc[mt][nt], 0, 0, 0);
#pragma unroll
      for (int mt = 0; mt < 2; ++mt)
#pragma unroll
        for (int nt = 0; nt < 2; ++nt)
          acc[mt][nt] = __builtin_amdgcn_mfma_f32_32x32x16_f16(
              ah[mt], bl[nt][kh], acc[mt][nt], 0, 0, 0);
    }
    // stage next tile; prefetch one further
    if (s + 1 < nsteps) {
      *(hfrag*)&As[cur ^ 1][arow][ak] = f2h8(f0, f1);
      if (s + 2 < nsteps && aval) {
        const float* ap = aptr + (size_t)(s + 2) * 32;
        f0 = *(const float4*)(ap + 0);
        f1 = *(const float4*)(ap + 4);
      }
    }
    cur ^= 1;
  }
  // epilogue: C/D col=lane&31, row=(reg&3)+8*(reg>>2)+4*g2; fp16 out
#pragma unroll
  for (int nt = 0; nt < 2; ++nt) {
    const int col = colbase + nt * 32 + l31;
    const float b = bias[col];
#pragma unroll
    for (int mt = 0; mt < 2; ++mt)
#pragma unroll
      for (int r = 0; r < 16; ++r) {
        int row = row0 + mt * 32 + (r & 3) + 8 * (r >> 2) + 4 * g2;
        if (row < M)
          Ch[(size_t)row * HIDDEN + col] = f2h_bits(fmaxf(acc[mt][nt][r] + b, 0.f));
      }
  }
}

// ---------------------------------------------------------------------------
// Layer GEMM body: A = fp16 h global, B = split-f16 planes (coalesced),
// 2 passes, register dbuf one K-step ahead. Out: fp16 m' = dinv[row]*(A@B).
// ---------------------------------------------------------------------------
#define LG_LOAD(S, AA, BH, BL)                                          \
  {                                                                     \
    AA[0][0] = *(const hfrag*)(ap0 + (S) * 32);                         \
    AA[0][1] = *(const hfrag*)(ap0 + (S) * 32 + 16);                    \
    AA[1][0] = *(const hfrag*)(ap1 + (S) * 32);                         \
    AA[1][1] = *(const hfrag*)(ap1 + (S) * 32 + 16);                    \
    B_LOAD(S, BH, BL);                                                  \
  }

__device__ __forceinline__ void layer_gemm_body(
    int bx, const unsigned short* __restrict__ A, const short* __restrict__ Wt,
    const float* __restrict__ dinv, unsigned short* __restrict__ Cm, int M) {
  const int t = threadIdx.x;
  const int w = t >> 6, l = t & 63;
  const int g2 = l >> 5, l31 = l & 31;
  const int row0 = bx * 64;
  const int colbase = w * 64;

  facc16 acc[2][2];
#pragma unroll
  for (int i = 0; i < 2; ++i)
#pragma unroll
    for (int j = 0; j < 2; ++j) acc[i][j] = (facc16)(0.0f);

  int r0 = row0 + l31, r1 = row0 + 32 + l31;
  if (r0 >= M) r0 = M - 1;
  if (r1 >= M) r1 = M - 1;
  const unsigned short* ap0 = A + (size_t)r0 * HIDDEN + g2 * 8;
  const unsigned short* ap1 = A + (size_t)r1 * HIDDEN + g2 * 8;
  const short* wb = Wt + (size_t)w * 4096 + (size_t)l * 8;

  hfrag aA[2][2], bhA[2][2], blA[2][2];
  hfrag aB[2][2], bhB[2][2], blB[2][2];

  LG_LOAD(0, aA, bhA, blA);
#pragma unroll
  for (int s = 0; s < 8; s += 2) {
    if (s + 1 < 8) LG_LOAD(s + 1, aB, bhB, blB);
    TILE_COMPUTE(aA, bhA, blA);
    if (s + 2 < 8) LG_LOAD(s + 2, aA, bhA, blA);
    TILE_COMPUTE(aB, bhB, blB);
  }
#pragma unroll
  for (int mt = 0; mt < 2; ++mt)
#pragma unroll
    for (int r = 0; r < 16; ++r) {
      int row = row0 + mt * 32 + (r & 3) + 8 * (r >> 2) + 4 * g2;
      if (row >= M) continue;
      const float sc = dinv[row];
#pragma unroll
      for (int nt = 0; nt < 2; ++nt)
        Cm[(size_t)row * HIDDEN + colbase + nt * 32 + l31] =
            f2h_bits(acc[mt][nt][r] * sc);
    }
}

// ---------------------------------------------------------------------------
// MEGA1: proj GEMM (blocks [0,ngemm)) || dst-degree histogram (rest)
// ---------------------------------------------------------------------------
__global__ __launch_bounds__(256, 4) void k_mega1(
    const float* __restrict__ x, const short* __restrict__ Wt,
    const float* __restrict__ b_in, unsigned short* __restrict__ h0, int M,
    int K, const int* __restrict__ dst, int* __restrict__ deg, int E,
    int ngemm, int nhist) {
  if ((int)blockIdx.x < ngemm) {
    proj_body(blockIdx.x, x, Wt, b_in, h0, M, K);
  } else {
    const int b = blockIdx.x - ngemm;
    for (int e = b * 256 + threadIdx.x; e < E; e += nhist * 256)
      atomicAdd(&deg[dst[e]], 1);
  }
}

// ---------------------------------------------------------------------------
// MEGA2: layer-0 GEMM (blocks [0,ngemm)) || CSR fill (rest)
// ---------------------------------------------------------------------------
__global__ __launch_bounds__(256, 2) void k_mega2(
    const unsigned short* __restrict__ h0, const short* __restrict__ WtL,
    const float* __restrict__ dinv, unsigned short* __restrict__ h1, int M,
    const int* __restrict__ src, const int* __restrict__ dst,
    const int* __restrict__ row_ptr, int* __restrict__ fill,
    int* __restrict__ csr, int E, int ngemm, int nfill) {
  if ((int)blockIdx.x < ngemm) {
    layer_gemm_body(blockIdx.x, h0, WtL, dinv, h1, M);
  } else {
    const int b = blockIdx.x - ngemm;
    for (int e = b * 256 + threadIdx.x; e < E; e += nfill * 256) {
      int d = dst[e];
      int pos = atomicAdd(&fill[d], 1);
      csr[row_ptr[d] + pos] = src[e];
    }
  }
}

__global__ __launch_bounds__(256, 2) void k_gemm_layer(
    const unsigned short* __restrict__ h, const short* __restrict__ WtL,
    const float* __restrict__ dinv, unsigned short* __restrict__ m, int M) {
  layer_gemm_body(blockIdx.x, h, WtL, dinv, m, M);
}

// ---------------------------------------------------------------------------
// Gather aggregation + bias + BN + ReLU over fp16 m'; fp16 h out.
// TWO nodes per wave: half-wave (32 lanes) covers one 512B row; lane owns
// 8 channels (uint4 = 16B). 8-row unroll.
// ---------------------------------------------------------------------------
__device__ inline void addrow8(float* acc, const uint4& r) {
  const unsigned short* p = (const unsigned short*)&r;
#pragma unroll
  for (int j = 0; j < 8; ++j) acc[j] += h2f(p[j]);
}

__global__ __launch_bounds__(256) void k_aggregate(
    const unsigned short* __restrict__ mp, const int* __restrict__ row_ptr,
    const int* __restrict__ csr, const float* __restrict__ dinv,
    const float* __restrict__ bg, const float* __restrict__ gamma,
    const float* __restrict__ beta, const float* __restrict__ mean,
    const float* __restrict__ var, unsigned short* __restrict__ hout, int N) {
  const int wave = threadIdx.x >> 6, l = threadIdx.x & 63;
  const int half = l >> 5, l31 = l & 31;
  const int v = blockIdx.x * 8 + wave * 2 + half;
  if (v >= N) return;
  const int co = l31 << 3;  // 8 channels per lane
  float acc[8];
  {
    uint4 rs = *(const uint4*)(mp + (size_t)v * HIDDEN + co);  // self loop
    const unsigned short* p = (const unsigned short*)&rs;
#pragma unroll
    for (int j = 0; j < 8; ++j) acc[j] = h2f(p[j]);
  }
  const int s = row_ptr[v], e = row_ptr[v + 1];
  int i = s;
  for (; i + 8 <= e; i += 8) {
    uint4 r[8];
#pragma unroll
    for (int j = 0; j < 8; ++j)
      r[j] = *(const uint4*)(mp + (size_t)csr[i + j] * HIDDEN + co);
#pragma unroll
    for (int j = 0; j < 8; ++j) addrow8(acc, r[j]);
  }
  for (; i < e; ++i) {
    uint4 r0 = *(const uint4*)(mp + (size_t)csr[i] * HIDDEN + co);
    addrow8(acc, r0);
  }
  const float dv = dinv[v];
  float4 g4a = *(const float4*)&gamma[co], g4b = *(const float4*)&gamma[co + 4];
  float4 vr4a = *(const float4*)&var[co], vr4b = *(const float4*)&var[co + 4];
  float4 bg4a = *(const float4*)&bg[co], bg4b = *(const float4*)&bg[co + 4];
  float4 mn4a = *(const float4*)&mean[co], mn4b = *(const float4*)&mean[co + 4];
  float4 be4a = *(const float4*)&beta[co], be4b = *(const float4*)&beta[co + 4];
  float sc[8] = {g4a.x / sqrtf(vr4a.x + 1e-5f), g4a.y / sqrtf(vr4a.y + 1e-5f),
                 g4a.z / sqrtf(vr4a.z + 1e-5f), g4a.w / sqrtf(vr4a.w + 1e-5f),
                 g4b.x / sqrtf(vr4b.x + 1e-5f), g4b.y / sqrtf(vr4b.y + 1e-5f),
                 g4b.z / sqrtf(vr4b.z + 1e-5f), g4b.w / sqrtf(vr4b.w + 1e-5f)};
  float ofs[8] = {bg4a.x - mn4a.x, bg4a.y - mn4a.y, bg4a.z - mn4a.z,
                  bg4a.w - mn4a.w, bg4b.x - mn4b.x, bg4b.y - mn4b.y,
                  bg4b.z - mn4b.z, bg4b.w - mn4b.w};
  float bt[8] = {be4a.x, be4a.y, be4a.z, be4a.w, be4b.x, be4b.y, be4b.z, be4b.w};
  unsigned short o[8];
#pragma unroll
  for (int j = 0; j < 8; ++j)
    o[j] = f2h_bits(fmaxf((acc[j] * dv + ofs[j]) * sc[j] + bt[j], 0.f));
  *(uint4*)&hout[(size_t)v * HIDDEN + co] = *(const uint4*)o;
}

// ---------------------------------------------------------------------------
// Mean pool: per-256-node block, per-channel running sum, atomics only at
// graph boundaries (batch sorted).
// ---------------------------------------------------------------------------
__global__ __launch_bounds__(256) void k_pool(const unsigned short* __restrict__ h,
                                              const int* __restrict__ batch,
                                              float* __restrict__ sums, int N) {
  const int t = threadIdx.x;
  const int start = blockIdx.x * 256;
  if (start >= N) return;
  const int end = min(start + 256, N);
  float acc = 0.f;
  int cur = batch[start];
  for (int n = start; n < end; ++n) {
    int g = batch[n];
    if (g != cur) {
      atomicAdd(&sums[cur * HIDDEN + t], acc);
      acc = 0.f;
      cur = g;
    }
    acc += h2f(h[(size_t)n * HIDDEN + t]);
  }
  atomicAdd(&sums[cur * HIDDEN + t], acc);
}

// ---------------------------------------------------------------------------
// Head MLP (+fused per-graph count via binary search; batch sorted):
// out = relu(g@W1+b1)@W2+b2, one block per graph
// ---------------------------------------------------------------------------
__global__ __launch_bounds__(128) void k_head(const float* __restrict__ sums,
                                              const int* __restrict__ batch,
                                              int N,
                                              const float* __restrict__ W1,
                                              const float* __restrict__ b1,
                                              const float* __restrict__ W2,
                                              const float* __restrict__ b2,
                                              float* __restrict__ out) {
  __shared__ float gr[256];
  __shared__ float t1[128];
  __shared__ float invs;
  const int b = blockIdx.x, t = threadIdx.x;
  if (t == 0) {
    int lo = 0, hi = N;
    while (lo < hi) {
      int mid = (lo + hi) >> 1;
      if (batch[mid] < b) lo = mid + 1; else hi = mid;
    }
    int lo2 = lo, hi2 = N;
    while (lo2 < hi2) {
      int mid = (lo2 + hi2) >> 1;
      if (batch[mid] < b + 1) lo2 = mid + 1; else hi2 = mid;
    }
    invs = 1.0f / fmaxf((float)(lo2 - lo), 1.0f);
  }
  __syncthreads();
  const float inv = invs;
  gr[t] = sums[b * HIDDEN + t] * inv;
  gr[t + 128] = sums[b * HIDDEN + t + 128] * inv;
  __syncthreads();
  float a = b1[t];
  for (int k = 0; k < 256; ++k) a += gr[k] * W1[k * 128 + t];
  t1[t] = fmaxf(a, 0.f);
  __syncthreads();
  float o = b2[t];
  for (int k = 0; k < 128; ++k) o += t1[k] * W2[k * 128 + t];
  out[b * 128 + t] = o;
}

// ---------------------------------------------------------------------------
extern "C" void kernel_launch(void* const* d_in, const int* in_sizes, int n_in,
                              void* d_out, int out_size, void* d_ws,
                              size_t ws_size, hipStream_t stream) {
  (void)n_in;
  (void)ws_size;
  const float* x = (const float*)d_in[0];
  const int* ei = (const int*)d_in[1];
  const int* batch = (const int*)d_in[2];
  const float* W_in = (const float*)d_in[3];
  const float* b_in = (const float*)d_in[4];
  const float* W_g = (const float*)d_in[5];
  const float* b_g = (const float*)d_in[6];
  const float* bn_gamma = (const float*)d_in[7];
  const float* bn_beta = (const float*)d_in[8];
  const float* bn_mean = (const float*)d_in[9];
  const float* bn_var = (const float*)d_in[10];
  const float* W1 = (const float*)d_in[11];
  const float* b1 = (const float*)d_in[12];
  const float* W2 = (const float*)d_in[13];
  const float* b2 = (const float*)d_in[14];

  const int KIN = 768;
  const int N = in_sizes[0] / KIN;   // 100000
  const int E = in_sizes[1] / 2;     // 1600000
  const int G = out_size / 128;      // 64

  const int* src = ei;
  const int* dst = ei + E;

  char* ws = (char*)d_ws;
  size_t off = 0;
  auto take = [&](size_t bytes) -> void* {
    void* p = ws + off;
    off += (bytes + 255) & ~(size_t)255;
    return p;
  };
  unsigned short* h0 = (unsigned short*)take((size_t)N * HIDDEN * 2);  // fp16 h
  unsigned short* h1 = (unsigned short*)take((size_t)N * HIDDEN * 2);  // fp16 m'
  float* dinv = (float*)take((size_t)N * 4);
  int* deg = (int*)take((size_t)N * 4);
  int* fill = (int*)take((size_t)N * 4);
  int* row_ptr = (int*)take((size_t)(N + 1) * 4);
  int* csr = (int*)take((size_t)E * 4);
  float* sums = (float*)take((size_t)G * HIDDEN * 4);
  short* Wt = (short*)take((size_t)(393216 + 3 * 131072) * 2);
  const int nb = (N + 255) / 256;
  int* bsum = (int*)take((size_t)nb * 4);
  int* boff = (int*)take((size_t)nb * 4);

  const int gx = (N + 63) / 64;
  const int NH = 256;  // hist blocks in mega1
  const int NF = 256;  // fill blocks in mega2

  // prep (also zeroes deg/fill/sums; its grid covers all)
  k_prep_w<<<(196608 + 3 * 65536 + 255) / 256, 256, 0, stream>>>(
      W_in, W_g, Wt, deg, fill, N, sums, G * HIDDEN);
  // proj GEMM || hist
  k_mega1<<<gx + NH, 256, 0, stream>>>(x, Wt, b_in, h0, N, KIN, dst, deg, E,
                                       gx, NH);
  k_scan_a<<<nb, 256, 0, stream>>>(deg, bsum, N);
  k_scan_b<<<1, 512, 0, stream>>>(bsum, boff, nb);
  k_scan_c<<<nb, 256, 0, stream>>>(deg, boff, row_ptr, dinv, N);
  // layer-0 GEMM || fill   (h0 -> h1 = m')
  k_mega2<<<gx + NF, 256, 0, stream>>>(h0, Wt + 393216, dinv, h1, N, src, dst,
                                       row_ptr, fill, csr, E, gx, NF);
  k_aggregate<<<(N + 7) / 8, 256, 0, stream>>>(
      h1, row_ptr, csr, dinv, b_g, bn_gamma, bn_beta, bn_mean, bn_var, h0, N);
  for (int i = 1; i < 3; ++i) {
    k_gemm_layer<<<gx, 256, 0, stream>>>(h0, Wt + 393216 + (size_t)i * 131072,
                                         dinv, h1, N);
    k_aggregate<<<(N + 7) / 8, 256, 0, stream>>>(
        h1, row_ptr, csr, dinv, b_g + i * HIDDEN, bn_gamma + i * HIDDEN,
        bn_beta + i * HIDDEN, bn_mean + i * HIDDEN, bn_var + i * HIDDEN, h0, N);
  }
  k_pool<<<(N + 255) / 256, 256, 0, stream>>>(h0, batch, sums, N);
  k_head<<<G, 128, 0, stream>>>(sums, batch, N, W1, b1, W2, b2, (float*)d_out);
}

// Round 23
// 930.412 us; speedup vs baseline: 1.0326x; 1.0042x over previous
//
#include <hip/hip_runtime.h>
#include <hip/hip_fp16.h>

#define HIDDEN 256

using hfrag = __attribute__((ext_vector_type(8))) _Float16;  // 8 fp16
using facc16 = __attribute__((ext_vector_type(16))) float;   // 32x32 accum

// lgkm-only barrier: ds ops flushed, global loads STAY IN FLIGHT
#define BARRIER_LGKM()                                   \
  do {                                                   \
    asm volatile("s_waitcnt lgkmcnt(0)" ::: "memory");   \
    __builtin_amdgcn_s_barrier();                        \
  } while (0)

__device__ inline float h2f(unsigned short h) {
  return __half2float(__builtin_bit_cast(__half, h));
}
__device__ inline unsigned short f2h_bits(float v) {
  return __builtin_bit_cast(unsigned short, __float2half(v));
}
// 8 fp32 -> 8 fp16
__device__ inline hfrag f2h8(const float4& a, const float4& b) {
  hfrag h;
  h[0] = (_Float16)a.x; h[1] = (_Float16)a.y;
  h[2] = (_Float16)a.z; h[3] = (_Float16)a.w;
  h[4] = (_Float16)b.x; h[5] = (_Float16)b.y;
  h[6] = (_Float16)b.z; h[7] = (_Float16)b.w;
  return h;
}

// ---------------------------------------------------------------------------
// Parallel scan for CSR row_ptr (+fused dinv)
// ---------------------------------------------------------------------------
__global__ __launch_bounds__(256) void k_scan_a(const int* __restrict__ deg,
                                                int* __restrict__ bsum, int N) {
  const int t = threadIdx.x, lane = t & 63, w = t >> 6;
  const int idx = blockIdx.x * 256 + t;
  int x = (idx < N) ? deg[idx] : 0;
#pragma unroll
  for (int off = 32; off >= 1; off >>= 1) x += __shfl_xor(x, off);
  __shared__ int ws[4];
  if (lane == 0) ws[w] = x;
  __syncthreads();
  if (t == 0) bsum[blockIdx.x] = ws[0] + ws[1] + ws[2] + ws[3];
}

__global__ __launch_bounds__(512) void k_scan_b(const int* __restrict__ bsum,
                                                int* __restrict__ boff, int nb) {
  const int t = threadIdx.x, lane = t & 63, w = t >> 6;
  int orig = (t < nb) ? bsum[t] : 0;
  int x = orig;
#pragma unroll
  for (int off = 1; off < 64; off <<= 1) {
    int y = __shfl_up(x, off);
    if (lane >= off) x += y;
  }
  __shared__ int wsum[8];
  if (lane == 63) wsum[w] = x;
  __syncthreads();
  if (w == 0 && lane < 8) {
    int s = wsum[lane];
#pragma unroll
    for (int off = 1; off < 8; off <<= 1) {
      int y = __shfl_up(s, off);
      if (lane >= off) s += y;
    }
    wsum[lane] = s;
  }
  __syncthreads();
  int inc = x + (w > 0 ? wsum[w - 1] : 0);
  if (t < nb) boff[t] = inc - orig;
}

__global__ __launch_bounds__(256) void k_scan_c(const int* __restrict__ deg,
                                                const int* __restrict__ boff,
                                                int* __restrict__ row_ptr,
                                                float* __restrict__ dinv, int N) {
  const int t = threadIdx.x, lane = t & 63, w = t >> 6;
  const int idx = blockIdx.x * 256 + t;
  int d = (idx < N) ? deg[idx] : 0;
  int x = d;
#pragma unroll
  for (int off = 1; off < 64; off <<= 1) {
    int y = __shfl_up(x, off);
    if (lane >= off) x += y;
  }
  __shared__ int ws[4];
  if (lane == 63) ws[w] = x;
  __syncthreads();
  int add = boff[blockIdx.x];
#pragma unroll
  for (int j = 0; j < 4; ++j)
    if (j < w) add += ws[j];
  if (idx < N) {
    row_ptr[idx + 1] = x + add;
    dinv[idx] = 1.0f / sqrtf((float)d + 1.0f);  // +1 self loop
  }
  if (idx == 0) row_ptr[0] = 0;
}

// ---------------------------------------------------------------------------
// Weight prep: split-f16 planes in WAVE-COALESCED fragment order (+ fused
// zeroing of deg/fill/sums). Per 32-k tile (16384 sh):
// [wave w (n>>6): 4096][frag nt*2+kh: 512, hi | +2048 lo][lane: 8][j].
// Offsets (shorts): W_in at 0 (24 tiles), layer l at 393216 + l*131072.
// ---------------------------------------------------------------------------
__global__ __launch_bounds__(256) void k_prep_w(const float* __restrict__ W_in,
                                                const float* __restrict__ W_g,
                                                short* __restrict__ Wt,
                                                int* __restrict__ deg,
                                                int* __restrict__ fill, int N,
                                                float* __restrict__ sums,
                                                int nsum) {
  const int e = blockIdx.x * blockDim.x + threadIdx.x;
  if (e < N) {
    deg[e] = 0;
    fill[e] = 0;
  }
  if (e < nsum) sums[e] = 0.f;
  if (e >= 196608 + 3 * 65536) return;
  float v;
  int k, n;
  size_t base;
  if (e < 196608) {           // W_in [768][256]
    k = e >> 8;
    n = e & 255;
    v = W_in[e];
    base = 0;
  } else {                    // W_g [3][256][256]
    int r = e - 196608;
    int lyr = r >> 16;
    k = (r >> 8) & 255;
    n = r & 255;
    v = W_g[r];
    base = 393216 + (size_t)lyr * 131072;
  }
  const int s = k >> 5;
  const int w = n >> 6, nt = (n >> 5) & 1, l31 = n & 31;
  const int kh = (k >> 4) & 1, g2 = (k >> 3) & 1, j = k & 7;
  size_t pos = base + (size_t)s * 16384 + (size_t)w * 4096 +
               (size_t)(nt * 2 + kh) * 512 + (size_t)(g2 * 32 + l31) * 8 + j;
  __half hh = __float2half(v);
  float r2 = v - __half2float(hh);
  Wt[pos] = (short)__builtin_bit_cast(unsigned short, hh);
  Wt[pos + 2048] = (short)__builtin_bit_cast(unsigned short, __float2half(r2));
}

// ---------------------------------------------------------------------------
// Shared B-load + MFMA macros (32x32x16_f16, wave tile 64x64, 2x2 frags)
// wb = Wt + w*4096 + lane*8 ; each load = contiguous 1KB per wave.
// ---------------------------------------------------------------------------
#define B_LOAD(S, BH, BL)                                               \
  {                                                                     \
    const short* wp = wb + ((size_t)(S) << 14);                         \
    BH[0][0] = *(const hfrag*)(wp);                                     \
    BH[0][1] = *(const hfrag*)(wp + 512);                               \
    BH[1][0] = *(const hfrag*)(wp + 1024);                              \
    BH[1][1] = *(const hfrag*)(wp + 1536);                              \
    BL[0][0] = *(const hfrag*)(wp + 2048);                              \
    BL[0][1] = *(const hfrag*)(wp + 2048 + 512);                        \
    BL[1][0] = *(const hfrag*)(wp + 2048 + 1024);                       \
    BL[1][1] = *(const hfrag*)(wp + 2048 + 1536);                       \
  }

#define TILE_COMPUTE(AA, BH, BL)                                        \
  _Pragma("unroll") for (int kh = 0; kh < 2; ++kh) {                    \
    _Pragma("unroll") for (int mt = 0; mt < 2; ++mt)                    \
        _Pragma("unroll") for (int nt = 0; nt < 2; ++nt) acc[mt][nt] =  \
        __builtin_amdgcn_mfma_f32_32x32x16_f16(AA[mt][kh], BH[nt][kh],  \
                                               acc[mt][nt], 0, 0, 0);   \
    _Pragma("unroll") for (int mt = 0; mt < 2; ++mt)                    \
        _Pragma("unroll") for (int nt = 0; nt < 2; ++nt) acc[mt][nt] =  \
        __builtin_amdgcn_mfma_f32_32x32x16_f16(AA[mt][kh], BL[nt][kh],  \
                                               acc[mt][nt], 0, 0, 0);   \
  }

// ---------------------------------------------------------------------------
// Proj GEMM body (R18 structure -- best measured): A = fp16(x) single,
// B = split-f16 2-pass single-buffered, 32x32x16_f16, LDS A-dbuf [2][64][34],
// lgkm barriers, A reg-prefetch. Out: fp16 h0 = relu(x@W_in + b_in).
// ---------------------------------------------------------------------------
__device__ __forceinline__ void proj_body(int bx, const float* __restrict__ A,
                                          const short* __restrict__ Wt,
                                          const float* __restrict__ bias,
                                          unsigned short* __restrict__ Ch,
                                          int M, int K) {
  __shared__ short As[2][64][34];  // fp16 A tile: 32 data + 2 pad
  const int t = threadIdx.x;
  const int w = t >> 6, l = t & 63;
  const int g2 = l >> 5, l31 = l & 31;
  const int row0 = bx * 64;
  const int colbase = w * 64;
  const int arow = t >> 2, ak = (t & 3) << 3;

  facc16 acc[2][2];
#pragma unroll
  for (int i = 0; i < 2; ++i)
#pragma unroll
    for (int j = 0; j < 2; ++j) acc[i][j] = (facc16)(0.0f);

  const int nsteps = K >> 5;
  const int ga = row0 + arow;
  const bool aval = ga < M;
  const float* aptr = A + (size_t)ga * K + ak;
  const short* wb = Wt + (size_t)w * 4096 + (size_t)l * 8;

  float4 f0 = make_float4(0.f, 0.f, 0.f, 0.f), f1 = f0;
  if (aval) {
    f0 = *(const float4*)aptr;
    f1 = *(const float4*)(aptr + 4);
  }
  *(hfrag*)&As[0][arow][ak] = f2h8(f0, f1);
  if (nsteps > 1 && aval) {
    f0 = *(const float4*)(aptr + 32);
    f1 = *(const float4*)(aptr + 36);
  }

  int cur = 0;
  for (int s = 0; s < nsteps; ++s) {
    BARRIER_LGKM();
    hfrag bh[2][2], bl[2][2];
    B_LOAD(s, bh, bl);
    // compute: per khalf, 2 A ds_reads + 8 MFMAs (2 passes)
#pragma unroll
    for (int kh = 0; kh < 2; ++kh) {
      hfrag ah[2];
#pragma unroll
      for (int mt = 0; mt < 2; ++mt)
        ah[mt] = *(const hfrag*)&As[cur][mt * 32 + l31][kh * 16 + g2 * 8];
#pragma unroll
      for (int mt = 0; mt < 2; ++mt)
#pragma unroll
        for (int nt = 0; nt < 2; ++nt)
          acc[mt][nt] = __builtin_amdgcn_mfma_f32_32x32x16_f16(
              ah[mt], bh[nt][kh], acc[mt][nt], 0, 0, 0);
#pragma unroll
      for (int mt = 0; mt < 2; ++mt)
#pragma unroll
        for (int nt = 0; nt < 2; ++nt)
          acc[mt][nt] = __builtin_amdgcn_mfma_f32_32x32x16_f16(
              ah[mt], bl[nt][kh], acc[mt][nt], 0, 0, 0);
    }
    // stage next tile; prefetch one further
    if (s + 1 < nsteps) {
      *(hfrag*)&As[cur ^ 1][arow][ak] = f2h8(f0, f1);
      if (s + 2 < nsteps && aval) {
        const float* ap = aptr + (size_t)(s + 2) * 32;
        f0 = *(const float4*)(ap + 0);
        f1 = *(const float4*)(ap + 4);
      }
    }
    cur ^= 1;
  }
  // epilogue: C/D col=lane&31, row=(reg&3)+8*(reg>>2)+4*g2; fp16 out
#pragma unroll
  for (int nt = 0; nt < 2; ++nt) {
    const int col = colbase + nt * 32 + l31;
    const float b = bias[col];
#pragma unroll
    for (int mt = 0; mt < 2; ++mt)
#pragma unroll
      for (int r = 0; r < 16; ++r) {
        int row = row0 + mt * 32 + (r & 3) + 8 * (r >> 2) + 4 * g2;
        if (row < M)
          Ch[(size_t)row * HIDDEN + col] = f2h_bits(fmaxf(acc[mt][nt][r] + b, 0.f));
      }
  }
}

// ---------------------------------------------------------------------------
// Layer GEMM body: A = fp16 h global, B = split-f16 planes (coalesced),
// 2 passes, register dbuf one K-step ahead. Out: fp16 m' = dinv[row]*(A@B).
// ---------------------------------------------------------------------------
#define LG_LOAD(S, AA, BH, BL)                                          \
  {                                                                     \
    AA[0][0] = *(const hfrag*)(ap0 + (S) * 32);                         \
    AA[0][1] = *(const hfrag*)(ap0 + (S) * 32 + 16);                    \
    AA[1][0] = *(const hfrag*)(ap1 + (S) * 32);                         \
    AA[1][1] = *(const hfrag*)(ap1 + (S) * 32 + 16);                    \
    B_LOAD(S, BH, BL);                                                  \
  }

__device__ __forceinline__ void layer_gemm_body(
    int bx, const unsigned short* __restrict__ A, const short* __restrict__ Wt,
    const float* __restrict__ dinv, unsigned short* __restrict__ Cm, int M) {
  const int t = threadIdx.x;
  const int w = t >> 6, l = t & 63;
  const int g2 = l >> 5, l31 = l & 31;
  const int row0 = bx * 64;
  const int colbase = w * 64;

  facc16 acc[2][2];
#pragma unroll
  for (int i = 0; i < 2; ++i)
#pragma unroll
    for (int j = 0; j < 2; ++j) acc[i][j] = (facc16)(0.0f);

  int r0 = row0 + l31, r1 = row0 + 32 + l31;
  if (r0 >= M) r0 = M - 1;
  if (r1 >= M) r1 = M - 1;
  const unsigned short* ap0 = A + (size_t)r0 * HIDDEN + g2 * 8;
  const unsigned short* ap1 = A + (size_t)r1 * HIDDEN + g2 * 8;
  const short* wb = Wt + (size_t)w * 4096 + (size_t)l * 8;

  hfrag aA[2][2], bhA[2][2], blA[2][2];
  hfrag aB[2][2], bhB[2][2], blB[2][2];

  LG_LOAD(0, aA, bhA, blA);
#pragma unroll
  for (int s = 0; s < 8; s += 2) {
    if (s + 1 < 8) LG_LOAD(s + 1, aB, bhB, blB);
    TILE_COMPUTE(aA, bhA, blA);
    if (s + 2 < 8) LG_LOAD(s + 2, aA, bhA, blA);
    TILE_COMPUTE(aB, bhB, blB);
  }
#pragma unroll
  for (int mt = 0; mt < 2; ++mt)
#pragma unroll
    for (int r = 0; r < 16; ++r) {
      int row = row0 + mt * 32 + (r & 3) + 8 * (r >> 2) + 4 * g2;
      if (row >= M) continue;
      const float sc = dinv[row];
#pragma unroll
      for (int nt = 0; nt < 2; ++nt)
        Cm[(size_t)row * HIDDEN + colbase + nt * 32 + l31] =
            f2h_bits(acc[mt][nt][r] * sc);
    }
}

// ---------------------------------------------------------------------------
// MEGA1: dst-degree histogram (blocks [0,nhist)) || proj GEMM (rest).
// Side-duty blocks FIRST: they dispatch before the GEMM wave-front so their
// atomic grind overlaps the whole GEMM rather than tailing past it.
// ---------------------------------------------------------------------------
__global__ __launch_bounds__(256, 4) void k_mega1(
    const float* __restrict__ x, const short* __restrict__ Wt,
    const float* __restrict__ b_in, unsigned short* __restrict__ h0, int M,
    int K, const int* __restrict__ dst, int* __restrict__ deg, int E,
    int ngemm, int nhist) {
  if ((int)blockIdx.x >= nhist) {
    proj_body(blockIdx.x - nhist, x, Wt, b_in, h0, M, K);
  } else {
    const int b = blockIdx.x;
    for (int e = b * 256 + threadIdx.x; e < E; e += nhist * 256)
      atomicAdd(&deg[dst[e]], 1);
  }
}

// ---------------------------------------------------------------------------
// MEGA2: CSR fill (blocks [0,nfill)) || layer-0 GEMM (rest)
// ---------------------------------------------------------------------------
__global__ __launch_bounds__(256, 2) void k_mega2(
    const unsigned short* __restrict__ h0, const short* __restrict__ WtL,
    const float* __restrict__ dinv, unsigned short* __restrict__ h1, int M,
    const int* __restrict__ src, const int* __restrict__ dst,
    const int* __restrict__ row_ptr, int* __restrict__ fill,
    int* __restrict__ csr, int E, int ngemm, int nfill) {
  if ((int)blockIdx.x >= nfill) {
    layer_gemm_body(blockIdx.x - nfill, h0, WtL, dinv, h1, M);
  } else {
    const int b = blockIdx.x;
    for (int e = b * 256 + threadIdx.x; e < E; e += nfill * 256) {
      int d = dst[e];
      int pos = atomicAdd(&fill[d], 1);
      csr[row_ptr[d] + pos] = src[e];
    }
  }
}

__global__ __launch_bounds__(256, 2) void k_gemm_layer(
    const unsigned short* __restrict__ h, const short* __restrict__ WtL,
    const float* __restrict__ dinv, unsigned short* __restrict__ m, int M) {
  layer_gemm_body(blockIdx.x, h, WtL, dinv, m, M);
}

// ---------------------------------------------------------------------------
// Gather aggregation + bias + BN + ReLU over fp16 m'; fp16 h out.
// TWO nodes per wave: half-wave (32 lanes) covers one 512B row; lane owns
// 8 channels (uint4 = 16B). 8-row unroll.
// ---------------------------------------------------------------------------
__device__ inline void addrow8(float* acc, const uint4& r) {
  const unsigned short* p = (const unsigned short*)&r;
#pragma unroll
  for (int j = 0; j < 8; ++j) acc[j] += h2f(p[j]);
}

__global__ __launch_bounds__(256) void k_aggregate(
    const unsigned short* __restrict__ mp, const int* __restrict__ row_ptr,
    const int* __restrict__ csr, const float* __restrict__ dinv,
    const float* __restrict__ bg, const float* __restrict__ gamma,
    const float* __restrict__ beta, const float* __restrict__ mean,
    const float* __restrict__ var, unsigned short* __restrict__ hout, int N) {
  const int wave = threadIdx.x >> 6, l = threadIdx.x & 63;
  const int half = l >> 5, l31 = l & 31;
  const int v = blockIdx.x * 8 + wave * 2 + half;
  if (v >= N) return;
  const int co = l31 << 3;  // 8 channels per lane
  float acc[8];
  {
    uint4 rs = *(const uint4*)(mp + (size_t)v * HIDDEN + co);  // self loop
    const unsigned short* p = (const unsigned short*)&rs;
#pragma unroll
    for (int j = 0; j < 8; ++j) acc[j] = h2f(p[j]);
  }
  const int s = row_ptr[v], e = row_ptr[v + 1];
  int i = s;
  for (; i + 8 <= e; i += 8) {
    uint4 r[8];
#pragma unroll
    for (int j = 0; j < 8; ++j)
      r[j] = *(const uint4*)(mp + (size_t)csr[i + j] * HIDDEN + co);
#pragma unroll
    for (int j = 0; j < 8; ++j) addrow8(acc, r[j]);
  }
  for (; i < e; ++i) {
    uint4 r0 = *(const uint4*)(mp + (size_t)csr[i] * HIDDEN + co);
    addrow8(acc, r0);
  }
  const float dv = dinv[v];
  float4 g4a = *(const float4*)&gamma[co], g4b = *(const float4*)&gamma[co + 4];
  float4 vr4a = *(const float4*)&var[co], vr4b = *(const float4*)&var[co + 4];
  float4 bg4a = *(const float4*)&bg[co], bg4b = *(const float4*)&bg[co + 4];
  float4 mn4a = *(const float4*)&mean[co], mn4b = *(const float4*)&mean[co + 4];
  float4 be4a = *(const float4*)&beta[co], be4b = *(const float4*)&beta[co + 4];
  float sc[8] = {g4a.x / sqrtf(vr4a.x + 1e-5f), g4a.y / sqrtf(vr4a.y + 1e-5f),
                 g4a.z / sqrtf(vr4a.z + 1e-5f), g4a.w / sqrtf(vr4a.w + 1e-5f),
                 g4b.x / sqrtf(vr4b.x + 1e-5f), g4b.y / sqrtf(vr4b.y + 1e-5f),
                 g4b.z / sqrtf(vr4b.z + 1e-5f), g4b.w / sqrtf(vr4b.w + 1e-5f)};
  float ofs[8] = {bg4a.x - mn4a.x, bg4a.y - mn4a.y, bg4a.z - mn4a.z,
                  bg4a.w - mn4a.w, bg4b.x - mn4b.x, bg4b.y - mn4b.y,
                  bg4b.z - mn4b.z, bg4b.w - mn4b.w};
  float bt[8] = {be4a.x, be4a.y, be4a.z, be4a.w, be4b.x, be4b.y, be4b.z, be4b.w};
  unsigned short o[8];
#pragma unroll
  for (int j = 0; j < 8; ++j)
    o[j] = f2h_bits(fmaxf((acc[j] * dv + ofs[j]) * sc[j] + bt[j], 0.f));
  *(uint4*)&hout[(size_t)v * HIDDEN + co] = *(const uint4*)o;
}

// ---------------------------------------------------------------------------
// Mean pool: per-256-node block, per-channel running sum, atomics only at
// graph boundaries (batch sorted).
// ---------------------------------------------------------------------------
__global__ __launch_bounds__(256) void k_pool(const unsigned short* __restrict__ h,
                                              const int* __restrict__ batch,
                                              float* __restrict__ sums, int N) {
  const int t = threadIdx.x;
  const int start = blockIdx.x * 256;
  if (start >= N) return;
  const int end = min(start + 256, N);
  float acc = 0.f;
  int cur = batch[start];
  for (int n = start; n < end; ++n) {
    int g = batch[n];
    if (g != cur) {
      atomicAdd(&sums[cur * HIDDEN + t], acc);
      acc = 0.f;
      cur = g;
    }
    acc += h2f(h[(size_t)n * HIDDEN + t]);
  }
  atomicAdd(&sums[cur * HIDDEN + t], acc);
}

// ---------------------------------------------------------------------------
// Head MLP (+fused per-graph count via binary search; batch sorted):
// out = relu(g@W1+b1)@W2+b2, one block per graph
// ---------------------------------------------------------------------------
__global__ __launch_bounds__(128) void k_head(const float* __restrict__ sums,
                                              const int* __restrict__ batch,
                                              int N,
                                              const float* __restrict__ W1,
                                              const float* __restrict__ b1,
                                              const float* __restrict__ W2,
                                              const float* __restrict__ b2,
                                              float* __restrict__ out) {
  __shared__ float gr[256];
  __shared__ float t1[128];
  __shared__ float invs;
  const int b = blockIdx.x, t = threadIdx.x;
  if (t == 0) {
    int lo = 0, hi = N;
    while (lo < hi) {
      int mid = (lo + hi) >> 1;
      if (batch[mid] < b) lo = mid + 1; else hi = mid;
    }
    int lo2 = lo, hi2 = N;
    while (lo2 < hi2) {
      int mid = (lo2 + hi2) >> 1;
      if (batch[mid] < b + 1) lo2 = mid + 1; else hi2 = mid;
    }
    invs = 1.0f / fmaxf((float)(lo2 - lo), 1.0f);
  }
  __syncthreads();
  const float inv = invs;
  gr[t] = sums[b * HIDDEN + t] * inv;
  gr[t + 128] = sums[b * HIDDEN + t + 128] * inv;
  __syncthreads();
  float a = b1[t];
  for (int k = 0; k < 256; ++k) a += gr[k] * W1[k * 128 + t];
  t1[t] = fmaxf(a, 0.f);
  __syncthreads();
  float o = b2[t];
  for (int k = 0; k < 128; ++k) o += t1[k] * W2[k * 128 + t];
  out[b * 128 + t] = o;
}

// ---------------------------------------------------------------------------
extern "C" void kernel_launch(void* const* d_in, const int* in_sizes, int n_in,
                              void* d_out, int out_size, void* d_ws,
                              size_t ws_size, hipStream_t stream) {
  (void)n_in;
  (void)ws_size;
  const float* x = (const float*)d_in[0];
  const int* ei = (const int*)d_in[1];
  const int* batch = (const int*)d_in[2];
  const float* W_in = (const float*)d_in[3];
  const float* b_in = (const float*)d_in[4];
  const float* W_g = (const float*)d_in[5];
  const float* b_g = (const float*)d_in[6];
  const float* bn_gamma = (const float*)d_in[7];
  const float* bn_beta = (const float*)d_in[8];
  const float* bn_mean = (const float*)d_in[9];
  const float* bn_var = (const float*)d_in[10];
  const float* W1 = (const float*)d_in[11];
  const float* b1 = (const float*)d_in[12];
  const float* W2 = (const float*)d_in[13];
  const float* b2 = (const float*)d_in[14];

  const int KIN = 768;
  const int N = in_sizes[0] / KIN;   // 100000
  const int E = in_sizes[1] / 2;     // 1600000
  const int G = out_size / 128;      // 64

  const int* src = ei;
  const int* dst = ei + E;

  char* ws = (char*)d_ws;
  size_t off = 0;
  auto take = [&](size_t bytes) -> void* {
    void* p = ws + off;
    off += (bytes + 255) & ~(size_t)255;
    return p;
  };
  unsigned short* h0 = (unsigned short*)take((size_t)N * HIDDEN * 2);  // fp16 h
  unsigned short* h1 = (unsigned short*)take((size_t)N * HIDDEN * 2);  // fp16 m'
  float* dinv = (float*)take((size_t)N * 4);
  int* deg = (int*)take((size_t)N * 4);
  int* fill = (int*)take((size_t)N * 4);
  int* row_ptr = (int*)take((size_t)(N + 1) * 4);
  int* csr = (int*)take((size_t)E * 4);
  float* sums = (float*)take((size_t)G * HIDDEN * 4);
  short* Wt = (short*)take((size_t)(393216 + 3 * 131072) * 2);
  const int nb = (N + 255) / 256;
  int* bsum = (int*)take((size_t)nb * 4);
  int* boff = (int*)take((size_t)nb * 4);

  const int gx = (N + 63) / 64;
  const int NH = 256;  // hist blocks in mega1
  const int NF = 256;  // fill blocks in mega2

  // prep (also zeroes deg/fill/sums; its grid covers all)
  k_prep_w<<<(196608 + 3 * 65536 + 255) / 256, 256, 0, stream>>>(
      W_in, W_g, Wt, deg, fill, N, sums, G * HIDDEN);
  // hist || proj GEMM (hist blocks first)
  k_mega1<<<gx + NH, 256, 0, stream>>>(x, Wt, b_in, h0, N, KIN, dst, deg, E,
                                       gx, NH);
  k_scan_a<<<nb, 256, 0, stream>>>(deg, bsum, N);
  k_scan_b<<<1, 512, 0, stream>>>(bsum, boff, nb);
  k_scan_c<<<nb, 256, 0, stream>>>(deg, boff, row_ptr, dinv, N);
  // fill || layer-0 GEMM (fill blocks first)   (h0 -> h1 = m')
  k_mega2<<<gx + NF, 256, 0, stream>>>(h0, Wt + 393216, dinv, h1, N, src, dst,
                                       row_ptr, fill, csr, E, gx, NF);
  k_aggregate<<<(N + 7) / 8, 256, 0, stream>>>(
      h1, row_ptr, csr, dinv, b_g, bn_gamma, bn_beta, bn_mean, bn_var, h0, N);
  for (int i = 1; i < 3; ++i) {
    k_gemm_layer<<<gx, 256, 0, stream>>>(h0, Wt + 393216 + (size_t)i * 131072,
                                         dinv, h1, N);
    k_aggregate<<<(N + 7) / 8, 256, 0, stream>>>(
        h1, row_ptr, csr, dinv, b_g + i * HIDDEN, bn_gamma + i * HIDDEN,
        bn_beta + i * HIDDEN, bn_mean + i * HIDDEN, bn_var + i * HIDDEN, h0, N);
  }
  k_pool<<<(N + 255) / 256, 256, 0, stream>>>(h0, batch, sums, N);
  k_head<<<G, 128, 0, stream>>>(sums, batch, N, W1, b1, W2, b2, (float*)d_out);
}